// Round 9
// baseline (387.144 us; speedup 1.0000x reference)
//
#include <hip/hip_runtime.h>
#include <hip/hip_bf16.h>
#include <math.h>

// Problem constants
constexpr int kD  = 1024;
constexpr int kH1 = 4096;
constexpr int kO  = 1024;
constexpr int kE  = 8;
constexpr int kB  = 8192;

constexpr int BM   = 128;            // row-tile
constexpr int MAXT = kB / BM + kE;   // 72 row-tiles upper bound

typedef __attribute__((ext_vector_type(8))) short short8;
typedef __attribute__((ext_vector_type(4))) float f32x4;

__device__ __forceinline__ unsigned short f2bf(float f) {
  unsigned int u = __float_as_uint(f);
  u += 0x7fffu + ((u >> 16) & 1u);
  return (unsigned short)(u >> 16);
}
__device__ __forceinline__ float bf2f(unsigned short u) {
  return __uint_as_float(((unsigned int)u) << 16);
}

// tanh-form gelu (max |err| vs erf-gelu ~1e-3, << bf16 noise)
__device__ __forceinline__ float gelu_fast(float x) {
  float u = 0.7978845608028654f * (x + 0.044715f * x * x * x);
  float eu = __expf(2.0f * u);
  float th = 1.0f - 2.0f / (eu + 1.0f);
  return 0.5f * x * (1.0f + th);
}

// pack 2 f32 -> u32 of 2 bf16 (RNE, elem0 in low 16)
__device__ __forceinline__ unsigned int pk2(float a, float b) {
  __hip_bfloat162 h = __float22bfloat162_rn(make_float2(a, b));
  return *reinterpret_cast<unsigned int*>(&h);
}

// ---------------------------------------------------------------------------
// Setup: per-expert counts, permutation, 128-row tile table.
// ---------------------------------------------------------------------------
__global__ __launch_bounds__(256) void setup_kernel(const int* __restrict__ eid,
                                                    int* __restrict__ perm,
                                                    int* __restrict__ tiles) {
  __shared__ int cnt[kE];
  __shared__ int off[kE];
  __shared__ int cur[kE];
  int t = threadIdx.x;
  if (t < kE) { cnt[t] = 0; cur[t] = 0; }
  __syncthreads();
  for (int i = t; i < kB; i += 256) atomicAdd(&cnt[eid[i]], 1);
  __syncthreads();
  if (t == 0) {
    int o = 0, nt = 0;
    for (int e = 0; e < kE; ++e) {
      off[e] = o;
      int c = cnt[e];
      for (int r = 0; r < c; r += BM) {
        tiles[nt * 4 + 0] = e;
        tiles[nt * 4 + 1] = o + r;
        tiles[nt * 4 + 2] = (c - r < BM) ? (c - r) : BM;
        tiles[nt * 4 + 3] = 0;
        ++nt;
      }
      o += c;
    }
    for (; nt < MAXT; ++nt) {
      tiles[nt * 4 + 0] = 0; tiles[nt * 4 + 1] = 0;
      tiles[nt * 4 + 2] = 0; tiles[nt * 4 + 3] = 0;
    }
  }
  __syncthreads();
  for (int i = t; i < kB; i += 256) {
    int e = eid[i];
    int p = off[e] + atomicAdd(&cur[e], 1);
    perm[p] = i;
  }
}

// ---------------------------------------------------------------------------
// Gather x rows into perm order, fp32 -> bf16.
// ---------------------------------------------------------------------------
__global__ __launch_bounds__(256) void gather_kernel(const float* __restrict__ x,
                                                     const int* __restrict__ perm,
                                                     unsigned short* __restrict__ xg) {
  int idx = blockIdx.x * 256 + threadIdx.x;
  int pos = idx >> 7;
  int c   = (idx & 127) << 3;
  int row = perm[pos];
  const float4* s = (const float4*)(x + (size_t)row * kD + c);
  float4 f0 = s[0], f1 = s[1];
  short8 v;
  v[0] = (short)f2bf(f0.x); v[1] = (short)f2bf(f0.y);
  v[2] = (short)f2bf(f0.z); v[3] = (short)f2bf(f0.w);
  v[4] = (short)f2bf(f1.x); v[5] = (short)f2bf(f1.y);
  v[6] = (short)f2bf(f1.z); v[7] = (short)f2bf(f1.w);
  *(short8*)(xg + (size_t)pos * kD + c) = v;
}

// ---------------------------------------------------------------------------
// Grouped GEMM, fp32 weights direct.  C[m][n] = sum_k A[m][k] * W[e][n][k].
// A bf16 [rows][KTOT] perm-space; W fp32 [kE][N][KTOT].
// 128x256 tile, BK=32, 8 waves (wave w: rows (w>>2)*64+0..63, col strips
// j*64+(w&3)*16).  LDS: 3 bufs x (A 8KB bf16 + B 32KB fp32) = 120KB.
// 5 glds issues/K-tile (A 1 + B 4), staged 2 K-tiles ahead, vmcnt(5)
// counted wait, ONE barrier per K-tile (reads land via lgkm before each
// wave's MFMA, which precedes the next barrier -> buffer reuse safe).
// Swizzles (2 lanes/16B-col = conflict-free):
//   A: paired-row layout [rr=r>>1][64]: elem slot c8 = ((r&1)*4+g)^(rr&7)
//   B: fp32 rows of 8 16B-slots: slot' = slot ^ (row&7)
// Staging writes linear LDS (t*16B); global source pre-inverse-swizzled.
// MODE 0: gelu->bf16 out_bf (perm space).  MODE 1 (split-K half from
// pancol>>2): half0 -> fp32 out_f scattered via perm; half1 -> bf16 out_bf.
// ---------------------------------------------------------------------------
template <int KTOT, int KTILES, int N, int NPAN, int MODE>
__global__ __launch_bounds__(512, 1) void gemmf_kernel(
    const unsigned short* __restrict__ Amat,
    const float* __restrict__ Wmat,
    const int* __restrict__ tiles,
    const int* __restrict__ perm,
    unsigned short* __restrict__ out_bf,
    float* __restrict__ out_f) {
  extern __shared__ char lds[];            // 3 x 40960
  constexpr int TOTAL = MAXT * NPAN;
  constexpr int nchN = NPAN / 4 > 0 ? NPAN / 4 : 1;

  // XCD-chunked swizzle: 16-block chunks cover 4 ti x 4 pancols.
  const int bid = blockIdx.x;
  const int id = (bid & 7) * (TOTAL / 8) + (bid >> 3);
  const int chunk = id >> 4;
  const int a16 = id & 15;
  const int ti = (chunk / nchN) * 4 + (a16 & 3);
  const int pancol = (chunk % nchN) * 4 + (a16 >> 2);

  int n0, kb, half;
  if constexpr (MODE == 0) {
    n0 = pancol * 256; kb = 0; half = 0;
  } else {
    half = pancol >> 2; n0 = (pancol & 3) * 256; kb = half * (KTOT / 2);
  }

  const int e  = tiles[ti * 4 + 0];
  const int rs = tiles[ti * 4 + 1];
  const int nr = tiles[ti * 4 + 2];
  if (nr == 0) return;

  const int t = threadIdx.x;
  const int l = t & 63;
  const int w = t >> 6;
  const int r0 = (w >> 2) * 64;
  const int wc16 = (w & 3) * 16;

  const unsigned short* Ab = Amat + (size_t)rs * KTOT + kb;
  const float* Bb = Wmat + ((size_t)e * N + n0) * KTOT + kb;

  // ---- staging source offsets (per-thread constants) ----
  // A (1 issue): thread t holds LDS elems 8t..8t+7: rr=t>>3, c8=t&7.
  const int s_rr = t >> 3, s_c8 = t & 7;
  const int s_v = s_c8 ^ (s_rr & 7);
  const size_t aSrc = (size_t)(s_rr * 2 + (s_v >> 2)) * KTOT + (s_v & 3) * 8;
  // B (4 issues i): f32 elem E=(i*512+t)*4: row=i*64+(t>>3), slot=t&7,
  // logical slot = (t&7)^((t>>3)&7)  (i*64 = 0 mod 8).
  const int bRow = t >> 3;
  const int bLs4 = ((t & 7) ^ ((t >> 3) & 7)) * 4;

  // ---- read offsets ----
  int offA[4];          // A lds short-elem offsets
#pragma unroll
  for (int mr = 0; mr < 4; ++mr) {
    int r = r0 + mr * 16 + (l & 15);
    int g = l >> 4;
    int rr = r >> 1;
    int c8 = (((r & 1) << 2) | g) ^ (rr & 7);
    offA[mr] = rr * 64 + c8 * 8;
  }
  int offB[4][2];       // B lds f32-elem offsets (float4-aligned)
#pragma unroll
  for (int j = 0; j < 4; ++j) {
    int rB = j * 64 + wc16 + (l & 15);
    int g = l >> 4;
#pragma unroll
    for (int h = 0; h < 2; ++h) {
      int s = (g * 2 + h) ^ (rB & 7);
      offB[j][h] = rB * 32 + s * 4;
    }
  }

  auto stage = [&](int buf, int k0) {
    char* base = lds + buf * 40960;
    // A: 8KB bf16
    __builtin_amdgcn_global_load_lds(
        (const __attribute__((address_space(1))) unsigned int*)(Ab + aSrc + k0),
        (__attribute__((address_space(3))) unsigned int*)(base + t * 16), 16, 0, 0);
    // B: 32KB fp32, 4 issues
#pragma unroll
    for (int i = 0; i < 4; ++i) {
      const float* src = Bb + (size_t)(i * 64 + bRow) * KTOT + k0 + bLs4;
      __builtin_amdgcn_global_load_lds(
          (const __attribute__((address_space(1))) unsigned int*)src,
          (__attribute__((address_space(3))) unsigned int*)(base + 8192 + (i * 512 + t) * 16),
          16, 0, 0);
    }
  };

  f32x4 acc[4][4] = {};   // [j][mr]

  // prologue: stage kt0, kt1
  stage(0, kb - kb + 0);
  stage(1, 32);
  // (kb already folded into Ab/Bb; k0 below is kt*32)

  int bcur = 0;
#pragma unroll 1
  for (int kt = 0; kt < KTILES; ++kt) {
    if (kt == KTILES - 1) asm volatile("s_waitcnt vmcnt(0)" ::: "memory");
    else                  asm volatile("s_waitcnt vmcnt(5)" ::: "memory");
    __builtin_amdgcn_s_barrier();
    char* base = lds + bcur * 40960;
    const unsigned short* As = (const unsigned short*)base;
    const float* Bs = (const float*)(base + 8192);
    short8 aF[4];
#pragma unroll
    for (int mr = 0; mr < 4; ++mr)
      aF[mr] = *(const short8*)(As + offA[mr]);
    float4 bFf[4][2];
#pragma unroll
    for (int j = 0; j < 4; ++j) {
      bFf[j][0] = *(const float4*)(Bs + offB[j][0]);
      bFf[j][1] = *(const float4*)(Bs + offB[j][1]);
    }
    if (kt < KTILES - 2) {
      int bst = bcur + 2; if (bst >= 3) bst -= 3;
      stage(bst, (kt + 2) * 32);
    }
    // cvt + MFMA (no second barrier needed: lgkm waits order reads->MFMA,
    // and MFMA precedes next barrier in program order for every wave)
    short8 bF[4];
#pragma unroll
    for (int j = 0; j < 4; ++j) {
      union { unsigned int u[4]; short8 v; } un;
      un.u[0] = pk2(bFf[j][0].x, bFf[j][0].y);
      un.u[1] = pk2(bFf[j][0].z, bFf[j][0].w);
      un.u[2] = pk2(bFf[j][1].x, bFf[j][1].y);
      un.u[3] = pk2(bFf[j][1].z, bFf[j][1].w);
      bF[j] = un.v;
    }
    __builtin_amdgcn_s_setprio(1);
#pragma unroll
    for (int j = 0; j < 4; ++j)
#pragma unroll
      for (int mr = 0; mr < 4; ++mr)
        acc[j][mr] = __builtin_amdgcn_mfma_f32_16x16x32_bf16(
            aF[mr], bF[j], acc[j][mr], 0, 0, 0);
    __builtin_amdgcn_s_setprio(0);
    ++bcur; if (bcur >= 3) bcur = 0;
  }

  // Epilogue.  D frag: row = r0+mr*16+(l>>4)*4+rg ; col = j*64+wc16+(l&15)
  const int lr4 = (l >> 4) * 4;
  const int lc  = l & 15;
#pragma unroll
  for (int mr = 0; mr < 4; ++mr)
#pragma unroll
    for (int rg = 0; rg < 4; ++rg) {
      int row = r0 + mr * 16 + lr4 + rg;
      if (row < nr) {
        if constexpr (MODE == 0) {
          unsigned short* dst = out_bf + (size_t)(rs + row) * N + n0;
#pragma unroll
          for (int j = 0; j < 4; ++j)
            dst[j * 64 + wc16 + lc] = f2bf(gelu_fast(acc[j][mr][rg]));
        } else {
          if (half == 0) {
            float* dst = out_f + (size_t)perm[rs + row] * N + n0;
#pragma unroll
            for (int j = 0; j < 4; ++j)
              dst[j * 64 + wc16 + lc] = acc[j][mr][rg];
          } else {
            unsigned short* dst = out_bf + (size_t)(rs + row) * N + n0;
#pragma unroll
            for (int j = 0; j < 4; ++j)
              dst[j * 64 + wc16 + lc] = f2bf(acc[j][mr][rg]);
          }
        }
      }
    }
}

// ---------------------------------------------------------------------------
// Reduce: y[orig] = y[orig](=partial0) + partial1(bf16, perm space) + b2[e].
// ---------------------------------------------------------------------------
__global__ __launch_bounds__(256) void reduce_kernel(float* __restrict__ y,
                                                     const unsigned short* __restrict__ part,
                                                     const int* __restrict__ perm,
                                                     const int* __restrict__ eid,
                                                     const float* __restrict__ b2) {
  int idx = blockIdx.x * 256 + threadIdx.x;
  int p = idx >> 7;
  int c = (idx & 127) << 3;
  int orig = perm[p];
  int e = eid[orig];
  float* yp = y + (size_t)orig * kO + c;
  short8 pv = *(const short8*)(part + (size_t)p * kO + c);
  const float* bp = b2 + (size_t)e * kO + c;
  float4 y0 = *(float4*)yp, y1 = *(float4*)(yp + 4);
  float4 b0 = *(const float4*)bp, b1 = *(const float4*)(bp + 4);
  y0.x += bf2f((unsigned short)pv[0]) + b0.x;
  y0.y += bf2f((unsigned short)pv[1]) + b0.y;
  y0.z += bf2f((unsigned short)pv[2]) + b0.z;
  y0.w += bf2f((unsigned short)pv[3]) + b0.w;
  y1.x += bf2f((unsigned short)pv[4]) + b1.x;
  y1.y += bf2f((unsigned short)pv[5]) + b1.y;
  y1.z += bf2f((unsigned short)pv[6]) + b1.z;
  y1.w += bf2f((unsigned short)pv[7]) + b1.w;
  *(float4*)yp = y0;
  *(float4*)(yp + 4) = y1;
}

// ---------------------------------------------------------------------------
extern "C" void kernel_launch(void* const* d_in, const int* in_sizes, int n_in,
                              void* d_out, int out_size, void* d_ws, size_t ws_size,
                              hipStream_t stream) {
  const float* x  = (const float*)d_in[0];
  const int*  eid = (const int*)d_in[1];
  const float* W1 = (const float*)d_in[2];
  const float* W2 = (const float*)d_in[3];
  const float* b2 = (const float*)d_in[4];
  float* y = (float*)d_out;

  char* ws = (char*)d_ws;
  int* perm  = (int*)ws;                                   // 32KB
  int* tiles = (int*)(ws + 32768);
  unsigned short* xg = (unsigned short*)(ws + 36864);      // [kB+256][kD] bf16
  size_t xg_bytes = (size_t)(kB + 256) * kD * 2;           // 17,301,504
  unsigned short* h  = (unsigned short*)(ws + 36864 + xg_bytes);  // [kB+256][kH1]

  auto g1 = gemmf_kernel<kD, 32, kH1, 16, 0>;
  auto g2 = gemmf_kernel<kH1, 64, kO, 8, 1>;
  hipFuncSetAttribute((const void*)g1, hipFuncAttributeMaxDynamicSharedMemorySize, 122880);
  hipFuncSetAttribute((const void*)g2, hipFuncAttributeMaxDynamicSharedMemorySize, 122880);

  setup_kernel<<<1, 256, 0, stream>>>(eid, perm, tiles);
  gather_kernel<<<(kB * kD / 8) / 256, 256, 0, stream>>>(x, perm, xg);

  // GEMM1: h = gelu(xg @ W1[e]^T)   (W1 fp32 direct)
  g1<<<MAXT * 16, 512, 122880, stream>>>(xg, W1, tiles, perm, h, nullptr);

  // GEMM2 split-K=2 (W2 fp32 direct): half0 -> y fp32 scattered,
  // half1 -> xg region (bf16, dead after GEMM1).
  g2<<<MAXT * 8, 512, 122880, stream>>>(h, W2, tiles, perm, xg, y);

  // y += partial1 + b2
  reduce_kernel<<<(kB * kO / 8) / 256, 256, 0, stream>>>(y, xg, perm, eid, b2);
}

// Round 10
// 319.549 us; speedup vs baseline: 1.2115x; 1.2115x over previous
//
#include <hip/hip_runtime.h>
#include <hip/hip_bf16.h>
#include <math.h>

// Problem constants
constexpr int kD  = 1024;
constexpr int kH1 = 4096;
constexpr int kO  = 1024;
constexpr int kE  = 8;
constexpr int kB  = 8192;

constexpr int BM = 256;            // row-tile
constexpr int MAXT = kB / BM + kE; // 40 row-tiles upper bound

typedef __attribute__((ext_vector_type(8))) short short8;
typedef __attribute__((ext_vector_type(4))) float f32x4;

__device__ __forceinline__ unsigned short f2bf(float f) {
  unsigned int u = __float_as_uint(f);
  u += 0x7fffu + ((u >> 16) & 1u);
  return (unsigned short)(u >> 16);
}

// tanh-form gelu (max |err| vs erf-gelu ~1e-3, << bf16 noise)
__device__ __forceinline__ float gelu_fast(float x) {
  float u = 0.7978845608028654f * (x + 0.044715f * x * x * x);
  float eu = __expf(2.0f * u);
  float th = 1.0f - 2.0f / (eu + 1.0f);
  return 0.5f * x * (1.0f + th);
}

// ---------------------------------------------------------------------------
// Setup: per-expert counts, permutation, 256-row tile table.
// ---------------------------------------------------------------------------
__global__ __launch_bounds__(256) void setup_kernel(const int* __restrict__ eid,
                                                    int* __restrict__ perm,
                                                    int* __restrict__ tiles) {
  __shared__ int cnt[kE];
  __shared__ int off[kE];
  __shared__ int cur[kE];
  int t = threadIdx.x;
  if (t < kE) { cnt[t] = 0; cur[t] = 0; }
  __syncthreads();
  for (int i = t; i < kB; i += 256) atomicAdd(&cnt[eid[i]], 1);
  __syncthreads();
  if (t == 0) {
    int o = 0, nt = 0;
    for (int e = 0; e < kE; ++e) {
      off[e] = o;
      int c = cnt[e];
      for (int r = 0; r < c; r += BM) {
        tiles[nt * 4 + 0] = e;
        tiles[nt * 4 + 1] = o + r;
        tiles[nt * 4 + 2] = (c - r < BM) ? (c - r) : BM;
        tiles[nt * 4 + 3] = 0;
        ++nt;
      }
      o += c;
    }
    for (; nt < MAXT; ++nt) {
      tiles[nt * 4 + 0] = 0; tiles[nt * 4 + 1] = 0;
      tiles[nt * 4 + 2] = 0; tiles[nt * 4 + 3] = 0;
    }
  }
  __syncthreads();
  for (int i = t; i < kB; i += 256) {
    int e = eid[i];
    int p = off[e] + atomicAdd(&cur[e], 1);
    perm[p] = i;
  }
}

// ---------------------------------------------------------------------------
// Fused gather (x -> xg bf16, perm order) + convert (W1 fp32 -> bf16).
// Unit = 8 elements per thread, grid-stride.
// ---------------------------------------------------------------------------
constexpr int kGN = kB * kD / 8;          // 1,048,576 gather units
constexpr int kCN = kE * kH1 * kD / 8;    // 4,194,304 W1 convert units

__global__ __launch_bounds__(256) void gatherconv_kernel(
    const float* __restrict__ x, const int* __restrict__ perm,
    unsigned short* __restrict__ xg,
    const float* __restrict__ W1, unsigned short* __restrict__ W1b) {
  const int stride = gridDim.x * 256;
  for (int u = blockIdx.x * 256 + threadIdx.x; u < kGN + kCN; u += stride) {
    const float4* s;
    unsigned short* d;
    if (u < kGN) {
      int pos = u >> 7;                    // kD/8 = 128 units per row
      int c   = (u & 127) << 3;
      s = (const float4*)(x + (size_t)perm[pos] * kD + c);
      d = xg + (size_t)pos * kD + c;
    } else {
      size_t v = (size_t)(u - kGN) * 8;
      s = (const float4*)(W1 + v);
      d = W1b + v;
    }
    float4 f0 = s[0], f1 = s[1];
    short8 o;
    o[0] = (short)f2bf(f0.x); o[1] = (short)f2bf(f0.y);
    o[2] = (short)f2bf(f0.z); o[3] = (short)f2bf(f0.w);
    o[4] = (short)f2bf(f1.x); o[5] = (short)f2bf(f1.y);
    o[6] = (short)f2bf(f1.z); o[7] = (short)f2bf(f1.w);
    *(short8*)d = o;
  }
}

// ---------------------------------------------------------------------------
// Standalone fp32 -> bf16 convert (fallback when ws too small for 2 bufs).
// ---------------------------------------------------------------------------
__global__ __launch_bounds__(256) void convert_kernel(const float* __restrict__ src,
                                                      unsigned short* __restrict__ dst,
                                                      int n8) {
  int stride = gridDim.x * 256;
  for (int i = blockIdx.x * 256 + threadIdx.x; i < n8; i += stride) {
    const float4* s = (const float4*)(src + (size_t)i * 8);
    float4 f0 = s[0], f1 = s[1];
    short8 v;
    v[0] = (short)f2bf(f0.x); v[1] = (short)f2bf(f0.y);
    v[2] = (short)f2bf(f0.z); v[3] = (short)f2bf(f0.w);
    v[4] = (short)f2bf(f1.x); v[5] = (short)f2bf(f1.y);
    v[6] = (short)f2bf(f1.z); v[7] = (short)f2bf(f1.w);
    *(short8*)(dst + (size_t)i * 8) = v;
  }
}

// ---------------------------------------------------------------------------
// 256x256 8-phase grouped GEMM (R5 structure, unchanged numerics).
// C = A(bf16,K-major) x B^T.  512 thr = 8 waves; BK=64; 2 LDS dbufs; slot
// order [A0,B0,B1,A1]; 1 half-tile staged/phase, 7 ahead; vmcnt(6) at
// K-tile starts; swizzle col ^= (row&7)<<3 source-side + ds_read (rule 21);
// 4ti x 4n0 XCD chunk swizzle; setprio around MFMA clusters.
// CONVTAIL: after the tile (incl. nr==0 blocks), grid-stride convert
// csrc fp32 -> cdst bf16 (kCN2 units) to hide the W2 convert under GEMM1.
// ---------------------------------------------------------------------------
constexpr int kCN2 = kE * kO * kH1 / 8;   // 4,194,304 W2 convert units

template <int K, int N, bool GELU, bool BIAS, bool OUTBF, bool CONVTAIL>
__global__ __launch_bounds__(512, 2) void gemm8p_kernel(
    const unsigned short* __restrict__ Amat,
    const unsigned short* __restrict__ Bmat,
    const float* __restrict__ bias,
    const int* __restrict__ tiles,
    const int* __restrict__ perm,
    unsigned short* __restrict__ out_bf,
    float* __restrict__ out_f,
    const float* __restrict__ csrc,
    unsigned short* __restrict__ cdst) {
  extern __shared__ unsigned short lds[];  // A: [2][2][8192], B at +32768
  constexpr int NKt = K / 64;
  constexpr int Npan = N / 256;

  // XCD-chunked block swizzle: 16-block chunks cover 4ti x 4n0.
  constexpr int total = MAXT * Npan;
  constexpr int cpx = total >> 3;
  constexpr int nchunks_n = (Npan >= 4) ? (Npan / 4) : 1;
  const int bid = blockIdx.x;
  const int id = (bid & 7) * cpx + (bid >> 3);
  const int chunk = id >> 4;
  const int a16 = id & 15;
  const int ti = (chunk / nchunks_n) * 4 + (a16 & 3);
  const int n0 = ((chunk % nchunks_n) * 4 + (a16 >> 2)) * 256;

  const int e  = tiles[ti * 4 + 0];
  const int rs = tiles[ti * 4 + 1];
  const int nr = tiles[ti * 4 + 2];

  const int t = threadIdx.x;
  const int l = t & 63;
  const int w = t >> 6;
  const int r0 = (w >> 2) * 64;   // 0 / 64
  const int c0 = (w & 3) * 32;    // 0 / 32 / 64 / 96

  if (nr != 0) {
    const unsigned short* Bp = Bmat + (size_t)e * N * K;

    auto ldsA = [&](int buf, int ha) { return lds + (buf * 2 + ha) * 8192; };
    auto ldsB = [&](int buf, int hb) { return lds + 32768 + (buf * 2 + hb) * 8192; };

    // Precomputed per-lane swizzled LDS element offsets (loop-invariant).
    int offA[4][2], offB[2][2];
#pragma unroll
    for (int mr = 0; mr < 4; ++mr)
#pragma unroll
      for (int ks = 0; ks < 2; ++ks) {
        int r = r0 + mr * 16 + (l & 15);
        offA[mr][ks] = r * 64 + ((ks * 32 + (l >> 4) * 8) ^ ((r & 7) << 3));
      }
#pragma unroll
    for (int nc = 0; nc < 2; ++nc)
#pragma unroll
      for (int ks = 0; ks < 2; ++ks) {
        int r = c0 + nc * 16 + (l & 15);
        offB[nc][ks] = r * 64 + ((ks * 32 + (l >> 4) * 8) ^ ((r & 7) << 3));
      }

    // Stage one half-tile (16KB): linear LDS dest, inverse-swizzled source.
    auto stage = [&](int H) {
      const int slot = H & 3;  // 0:A r0-127  1:B c0-127  2:B c128-255  3:A r128-255
      const int ktS = H >> 2, buf = ktS & 1, k0 = ktS * 64;
#pragma unroll
      for (int i = 0; i < 2; ++i) {
        int elem = (i * 512 + t) * 8;
        int r = elem >> 6, cp = elem & 63;
        int cl = cp ^ ((r & 7) << 3);
        const unsigned short* src;
        unsigned short* dst;
        if (slot == 0 || slot == 3) {
          src = Amat + (size_t)(rs + (slot == 3 ? 128 : 0) + r) * K + k0 + cl;
          dst = ldsA(buf, slot == 3 ? 1 : 0) + elem;
        } else {
          src = Bp + (size_t)(n0 + (slot == 2 ? 128 : 0) + r) * K + k0 + cl;
          dst = ldsB(buf, slot == 2 ? 1 : 0) + elem;
        }
        __builtin_amdgcn_global_load_lds(
            (const __attribute__((address_space(1))) unsigned int*)src,
            (__attribute__((address_space(3))) unsigned int*)dst, 16, 0, 0);
      }
    };

    short8 aF[4][2], bF0[2][2], bF1[2][2];
    f32x4 acc[2][2][4][2] = {};

    auto loadA = [&](int buf, int ha) {
      const unsigned short* base = ldsA(buf, ha);
#pragma unroll
      for (int mr = 0; mr < 4; ++mr)
#pragma unroll
        for (int ks = 0; ks < 2; ++ks)
          aF[mr][ks] = *(const short8*)(base + offA[mr][ks]);
    };
    auto loadB = [&](int buf, int hb, short8 (*bF)[2]) {
      const unsigned short* base = ldsB(buf, hb);
#pragma unroll
      for (int nc = 0; nc < 2; ++nc)
#pragma unroll
        for (int ks = 0; ks < 2; ++ks)
          bF[nc][ks] = *(const short8*)(base + offB[nc][ks]);
    };
    auto mfmaQ = [&](int qr, int qc, short8 (*bF)[2]) {
      __builtin_amdgcn_s_setprio(1);
#pragma unroll
      for (int mr = 0; mr < 4; ++mr)
#pragma unroll
        for (int nc = 0; nc < 2; ++nc)
#pragma unroll
          for (int ks = 0; ks < 2; ++ks)
            acc[qr][qc][mr][nc] = __builtin_amdgcn_mfma_f32_16x16x32_bf16(
                aF[mr][ks], bF[nc][ks], acc[qr][qc][mr][nc], 0, 0, 0);
      __builtin_amdgcn_s_setprio(0);
    };

    // Prologue: K-tile 0 fully + first 3 halves of K-tile 1.
#pragma unroll
    for (int H = 0; H < 4; ++H) stage(H);
    asm volatile("s_waitcnt vmcnt(4)" ::: "memory");
#pragma unroll
    for (int H = 4; H < 7; ++H) stage(H);

    for (int kt = 0; kt < NKt - 1; ++kt) {
      const int buf = kt & 1;
      asm volatile("s_waitcnt vmcnt(6)" ::: "memory");
      __builtin_amdgcn_s_barrier();
      loadA(buf, 0);
      loadB(buf, 0, bF0);
      { int H = 4 * kt + 7;  if (H < 4 * NKt) stage(H); }
      __builtin_amdgcn_s_barrier();
      mfmaQ(0, 0, bF0);
      __builtin_amdgcn_s_barrier();
      loadB(buf, 1, bF1);
      { int H = 4 * kt + 8;  if (H < 4 * NKt) stage(H); }
      __builtin_amdgcn_s_barrier();
      mfmaQ(0, 1, bF1);
      __builtin_amdgcn_s_barrier();
      loadA(buf, 1);
      { int H = 4 * kt + 9;  if (H < 4 * NKt) stage(H); }
      __builtin_amdgcn_s_barrier();
      mfmaQ(1, 0, bF0);
      __builtin_amdgcn_s_barrier();
      { int H = 4 * kt + 10; if (H < 4 * NKt) stage(H); }
      __builtin_amdgcn_s_barrier();
      mfmaQ(1, 1, bF1);
    }
    {
      const int buf = (NKt - 1) & 1;
      asm volatile("s_waitcnt vmcnt(0)" ::: "memory");
      __builtin_amdgcn_s_barrier();
      loadA(buf, 0);
      loadB(buf, 0, bF0);
      __builtin_amdgcn_s_barrier();
      mfmaQ(0, 0, bF0);
      __builtin_amdgcn_s_barrier();
      loadB(buf, 1, bF1);
      __builtin_amdgcn_s_barrier();
      mfmaQ(0, 1, bF1);
      __builtin_amdgcn_s_barrier();
      loadA(buf, 1);
      __builtin_amdgcn_s_barrier();
      mfmaQ(1, 0, bF0);
      __builtin_amdgcn_s_barrier();
      mfmaQ(1, 1, bF1);
    }

    // Epilogue.
    const int lr4 = (l >> 4) * 4;
    const int lc  = l & 15;
#pragma unroll
    for (int qr = 0; qr < 2; ++qr)
#pragma unroll
      for (int mr = 0; mr < 4; ++mr)
#pragma unroll
        for (int rg = 0; rg < 4; ++rg) {
          int row = qr * 128 + r0 + mr * 16 + lr4 + rg;
          if (row < nr) {
            if constexpr (OUTBF) {
              unsigned short* dst = out_bf + (size_t)(rs + row) * N + n0;
#pragma unroll
              for (int qc = 0; qc < 2; ++qc)
#pragma unroll
                for (int nc = 0; nc < 2; ++nc) {
                  float v = acc[qr][qc][mr][nc][rg];
                  if constexpr (GELU) v = gelu_fast(v);
                  dst[qc * 128 + c0 + nc * 16 + lc] = f2bf(v);
                }
            } else {
              int orig = perm[rs + row];
              float* dst = out_f + (size_t)orig * N + n0;
#pragma unroll
              for (int qc = 0; qc < 2; ++qc)
#pragma unroll
                for (int nc = 0; nc < 2; ++nc) {
                  float v = acc[qr][qc][mr][nc][rg];
                  if constexpr (BIAS)
                    v += bias[(size_t)e * N + n0 + qc * 128 + c0 + nc * 16 + lc];
                  dst[qc * 128 + c0 + nc * 16 + lc] = v;
                }
            }
          }
        }
  }

  if constexpr (CONVTAIL) {
    // Hide W2 fp32->bf16 under GEMM1: grid-stride over kCN2 vec8 units.
    const size_t stride = (size_t)gridDim.x * 512;
    for (size_t u = (size_t)bid * 512 + t; u < (size_t)kCN2; u += stride) {
      const float4* s = (const float4*)(csrc + u * 8);
      float4 f0 = s[0], f1 = s[1];
      short8 v;
      v[0] = (short)f2bf(f0.x); v[1] = (short)f2bf(f0.y);
      v[2] = (short)f2bf(f0.z); v[3] = (short)f2bf(f0.w);
      v[4] = (short)f2bf(f1.x); v[5] = (short)f2bf(f1.y);
      v[6] = (short)f2bf(f1.z); v[7] = (short)f2bf(f1.w);
      *(short8*)(cdst + u * 8) = v;
    }
  }
}

// ---------------------------------------------------------------------------
extern "C" void kernel_launch(void* const* d_in, const int* in_sizes, int n_in,
                              void* d_out, int out_size, void* d_ws, size_t ws_size,
                              hipStream_t stream) {
  const float* x  = (const float*)d_in[0];
  const int*  eid = (const int*)d_in[1];
  const float* W1 = (const float*)d_in[2];
  const float* W2 = (const float*)d_in[3];
  const float* b2 = (const float*)d_in[4];
  float* y = (float*)d_out;

  char* ws = (char*)d_ws;
  int* perm  = (int*)ws;                                   // 32KB
  int* tiles = (int*)(ws + 32768);
  unsigned short* xg = (unsigned short*)(ws + 36864);      // [kB+256][kD]
  size_t xg_bytes = (size_t)(kB + 256) * kD * 2;           // 17,301,504
  unsigned short* h  = (unsigned short*)(ws + 36864 + xg_bytes);
  size_t h_bytes = (size_t)(kB + 256) * kH1 * 2;           // 69,206,016
  size_t w1b_off = 36864 + xg_bytes + h_bytes;             // 86,545,152-ish
  unsigned short* W1b = (unsigned short*)(ws + w1b_off);   // 67,108,864
  size_t w2b_off = w1b_off + 67108864;
  const bool twobuf = ws_size >= w2b_off + 67108864;
  unsigned short* W2b = twobuf ? (unsigned short*)(ws + w2b_off) : W1b;

  auto g1f = gemm8p_kernel<kD, kH1, true, false, true, true>;   // conv tail
  auto g1s = gemm8p_kernel<kD, kH1, true, false, true, false>;  // no tail
  auto g2  = gemm8p_kernel<kH1, kO, false, true, false, false>;
  hipFuncSetAttribute((const void*)g1f, hipFuncAttributeMaxDynamicSharedMemorySize, 131072);
  hipFuncSetAttribute((const void*)g1s, hipFuncAttributeMaxDynamicSharedMemorySize, 131072);
  hipFuncSetAttribute((const void*)g2,  hipFuncAttributeMaxDynamicSharedMemorySize, 131072);

  setup_kernel<<<1, 256, 0, stream>>>(eid, perm, tiles);

  // gather + W1 convert fused (HBM-bound)
  gatherconv_kernel<<<2048, 256, 0, stream>>>(x, perm, xg, W1, W1b);

  if (twobuf) {
    // GEMM1 with W2-convert tail hidden under it
    g1f<<<MAXT * (kH1 / 256), 512, 131072, stream>>>(
        xg, W1b, nullptr, tiles, perm, h, nullptr, W2, W2b);
  } else {
    g1s<<<MAXT * (kH1 / 256), 512, 131072, stream>>>(
        xg, W1b, nullptr, tiles, perm, h, nullptr, nullptr, nullptr);
    convert_kernel<<<2048, 256, 0, stream>>>(W2, W2b, kCN2);
  }

  // GEMM2: y[orig] = h @ W2[e]^T + b2[e]
  g2<<<MAXT * (kO / 256), 512, 131072, stream>>>(
      h, W2b, b2, tiles, perm, nullptr, y, nullptr, nullptr);
}

// Round 11
// 315.808 us; speedup vs baseline: 1.2259x; 1.0118x over previous
//
#include <hip/hip_runtime.h>
#include <hip/hip_bf16.h>
#include <math.h>

// Problem constants
constexpr int kD  = 1024;
constexpr int kH1 = 4096;
constexpr int kO  = 1024;
constexpr int kE  = 8;
constexpr int kB  = 8192;

constexpr int BM = 256;            // row-tile
constexpr int MAXT = kB / BM + kE; // 40 row-tiles upper bound

typedef __attribute__((ext_vector_type(8))) short short8;
typedef __attribute__((ext_vector_type(4))) float f32x4;

__device__ __forceinline__ unsigned short f2bf(float f) {
  unsigned int u = __float_as_uint(f);
  u += 0x7fffu + ((u >> 16) & 1u);
  return (unsigned short)(u >> 16);
}

// tanh-form gelu (max |err| vs erf-gelu ~1e-3, << bf16 noise)
__device__ __forceinline__ float gelu_fast(float x) {
  float u = 0.7978845608028654f * (x + 0.044715f * x * x * x);
  float eu = __expf(2.0f * u);
  float th = 1.0f - 2.0f / (eu + 1.0f);
  return 0.5f * x * (1.0f + th);
}

// ---------------------------------------------------------------------------
// Setup: per-expert counts, permutation, 256-row tile table.
// ---------------------------------------------------------------------------
__global__ __launch_bounds__(256) void setup_kernel(const int* __restrict__ eid,
                                                    int* __restrict__ perm,
                                                    int* __restrict__ tiles) {
  __shared__ int cnt[kE];
  __shared__ int off[kE];
  __shared__ int cur[kE];
  int t = threadIdx.x;
  if (t < kE) { cnt[t] = 0; cur[t] = 0; }
  __syncthreads();
  for (int i = t; i < kB; i += 256) atomicAdd(&cnt[eid[i]], 1);
  __syncthreads();
  if (t == 0) {
    int o = 0, nt = 0;
    for (int e = 0; e < kE; ++e) {
      off[e] = o;
      int c = cnt[e];
      for (int r = 0; r < c; r += BM) {
        tiles[nt * 4 + 0] = e;
        tiles[nt * 4 + 1] = o + r;
        tiles[nt * 4 + 2] = (c - r < BM) ? (c - r) : BM;
        tiles[nt * 4 + 3] = 0;
        ++nt;
      }
      o += c;
    }
    for (; nt < MAXT; ++nt) {
      tiles[nt * 4 + 0] = 0; tiles[nt * 4 + 1] = 0;
      tiles[nt * 4 + 2] = 0; tiles[nt * 4 + 3] = 0;
    }
  }
  __syncthreads();
  for (int i = t; i < kB; i += 256) {
    int e = eid[i];
    int p = off[e] + atomicAdd(&cur[e], 1);
    perm[p] = i;
  }
}

// ---------------------------------------------------------------------------
// Fused gather (x -> xg bf16, perm order) + convert (W1 fp32 -> bf16).
// ---------------------------------------------------------------------------
constexpr int kGN = kB * kD / 8;
constexpr int kCN = kE * kH1 * kD / 8;

__global__ __launch_bounds__(256) void gatherconv_kernel(
    const float* __restrict__ x, const int* __restrict__ perm,
    unsigned short* __restrict__ xg,
    const float* __restrict__ W1, unsigned short* __restrict__ W1b) {
  const int stride = gridDim.x * 256;
  for (int u = blockIdx.x * 256 + threadIdx.x; u < kGN + kCN; u += stride) {
    const float4* s;
    unsigned short* d;
    if (u < kGN) {
      int pos = u >> 7;
      int c   = (u & 127) << 3;
      s = (const float4*)(x + (size_t)perm[pos] * kD + c);
      d = xg + (size_t)pos * kD + c;
    } else {
      size_t v = (size_t)(u - kGN) * 8;
      s = (const float4*)(W1 + v);
      d = W1b + v;
    }
    float4 f0 = s[0], f1 = s[1];
    short8 o;
    o[0] = (short)f2bf(f0.x); o[1] = (short)f2bf(f0.y);
    o[2] = (short)f2bf(f0.z); o[3] = (short)f2bf(f0.w);
    o[4] = (short)f2bf(f1.x); o[5] = (short)f2bf(f1.y);
    o[6] = (short)f2bf(f1.z); o[7] = (short)f2bf(f1.w);
    *(short8*)d = o;
  }
}

// ---------------------------------------------------------------------------
// Standalone fp32 -> bf16 convert (fallback when ws too small for 2 bufs).
// ---------------------------------------------------------------------------
__global__ __launch_bounds__(256) void convert_kernel(const float* __restrict__ src,
                                                      unsigned short* __restrict__ dst,
                                                      int n8) {
  int stride = gridDim.x * 256;
  for (int i = blockIdx.x * 256 + threadIdx.x; i < n8; i += stride) {
    const float4* s = (const float4*)(src + (size_t)i * 8);
    float4 f0 = s[0], f1 = s[1];
    short8 v;
    v[0] = (short)f2bf(f0.x); v[1] = (short)f2bf(f0.y);
    v[2] = (short)f2bf(f0.z); v[3] = (short)f2bf(f0.w);
    v[4] = (short)f2bf(f1.x); v[5] = (short)f2bf(f1.y);
    v[6] = (short)f2bf(f1.z); v[7] = (short)f2bf(f1.w);
    *(short8*)(dst + (size_t)i * 8) = v;
  }
}

// ---------------------------------------------------------------------------
// 256x256 8-phase grouped GEMM with IMMEDIATE-OFFSET ds_reads.
// LDS (128KB): [buf:64KB][q:16KB x4 = A0,A1,B0,B1][ks:8KB][row:128][64B row]
// Row = 4 x 16B slots; swizzle: phys_slot = logical_slot ^ ((row>>1)&3)
// (lane-invariant across mr/nc since 16-row steps preserve (row>>1)&3).
// Reads: 2 base VGPRs (A,B) + buf1 at +65536; all structural offsets are
// compile-time imms (buf folded by #pragma unroll 2).
// Staging: linear LDS dest (rule 21), source pre-inverse-swizzled; issue i
// covers ks=i.  Schedule identical to R5/R10: 8 phases, vmcnt(6) at K-tile
// starts, setprio around MFMA clusters, 4ti x 4n0 XCD chunk swizzle.
// CONVTAIL: grid-stride W2 fp32->bf16 after the tile (hides under GEMM1).
// ---------------------------------------------------------------------------
constexpr int kCN2 = kE * kO * kH1 / 8;

template <int K, int N, bool GELU, bool BIAS, bool OUTBF, bool CONVTAIL>
__global__ __launch_bounds__(512, 2) void gemm8p_kernel(
    const unsigned short* __restrict__ Amat,
    const unsigned short* __restrict__ Bmat,
    const float* __restrict__ bias,
    const int* __restrict__ tiles,
    const int* __restrict__ perm,
    unsigned short* __restrict__ out_bf,
    float* __restrict__ out_f,
    const float* __restrict__ csrc,
    unsigned short* __restrict__ cdst) {
  extern __shared__ char lds[];            // 131072 bytes
  constexpr int NKt = K / 64;
  constexpr int Npan = N / 256;

  constexpr int total = MAXT * Npan;
  constexpr int cpx = total >> 3;
  constexpr int nchunks_n = (Npan >= 4) ? (Npan / 4) : 1;
  const int bid = blockIdx.x;
  const int id = (bid & 7) * cpx + (bid >> 3);
  const int chunk = id >> 4;
  const int a16 = id & 15;
  const int ti = (chunk / nchunks_n) * 4 + (a16 & 3);
  const int n0 = ((chunk % nchunks_n) * 4 + (a16 >> 2)) * 256;

  const int e  = tiles[ti * 4 + 0];
  const int rs = tiles[ti * 4 + 1];
  const int nr = tiles[ti * 4 + 2];

  const int t = threadIdx.x;
  const int l = t & 63;
  const int w = t >> 6;
  const int r0 = (w >> 2) * 64;   // 0 / 64
  const int c0 = (w & 3) * 32;    // 0 / 32 / 64 / 96

  if (nr != 0) {
    const unsigned short* Bp = Bmat + (size_t)e * N * K;

    // ---- lane-variant read bases (byte addressing) ----
    const int rA = r0 + (l & 15);
    const int gA = l >> 4;
    char* vA0 = lds + rA * 64 + ((gA ^ ((rA >> 1) & 3)) * 16);
    const int rB = c0 + (l & 15);
    char* vB0 = lds + 32768 + rB * 64 + ((gA ^ ((rB >> 1) & 3)) * 16);
    char* vA1 = vA0 + 65536;
    char* vB1 = vB0 + 65536;

    // ---- staging constants: thread t -> row sR, phys slot t&3 ----
    const int sR = (t >> 2) & 127;
    const int sG = (t & 3) ^ ((sR >> 1) & 3);   // logical k-slot stored at phys t&3

    // One half-tile (16KB): 2 issues, issue i covers ks=i.
    auto stage = [&](int H) {
      const int slot = H & 3;   // 0:A r0-127  1:B c0-127  2:B c128-255  3:A r128-255
      const int ktS = H >> 2, buf = ktS & 1, k0 = ktS * 64;
      const int q = (slot == 0) ? 0 : (slot == 3) ? 1 : (slot == 1) ? 2 : 3;
      char* dq = lds + buf * 65536 + q * 16384;
      const unsigned short* srow;
      if (slot == 0)      srow = Amat + (size_t)(rs + sR) * K;
      else if (slot == 3) srow = Amat + (size_t)(rs + 128 + sR) * K;
      else if (slot == 1) srow = Bp + (size_t)(n0 + sR) * K;
      else                srow = Bp + (size_t)(n0 + 128 + sR) * K;
#pragma unroll
      for (int i = 0; i < 2; ++i) {
        const unsigned short* src = srow + k0 + i * 32 + sG * 8;
        __builtin_amdgcn_global_load_lds(
            (const __attribute__((address_space(1))) unsigned int*)src,
            (__attribute__((address_space(3))) unsigned int*)(dq + i * 8192 + t * 16),
            16, 0, 0);
      }
    };

    short8 aF[4][2], bF0[2][2], bF1[2][2];
    f32x4 acc[2][2][4][2] = {};

    // Reads: base + compile-time imm only.
    auto loadA = [&](char* vA, int ha) {
#pragma unroll
      for (int mr = 0; mr < 4; ++mr)
#pragma unroll
        for (int ks = 0; ks < 2; ++ks)
          aF[mr][ks] = *(const short8*)(vA + ha * 16384 + ks * 8192 + mr * 1024);
    };
    auto loadB = [&](char* vB, int hb, short8 (*bF)[2]) {
#pragma unroll
      for (int nc = 0; nc < 2; ++nc)
#pragma unroll
        for (int ks = 0; ks < 2; ++ks)
          bF[nc][ks] = *(const short8*)(vB + hb * 16384 + ks * 8192 + nc * 1024);
    };
    auto mfmaQ = [&](int qr, int qc, short8 (*bF)[2]) {
      __builtin_amdgcn_s_setprio(1);
#pragma unroll
      for (int mr = 0; mr < 4; ++mr)
#pragma unroll
        for (int nc = 0; nc < 2; ++nc)
#pragma unroll
          for (int ks = 0; ks < 2; ++ks)
            acc[qr][qc][mr][nc] = __builtin_amdgcn_mfma_f32_16x16x32_bf16(
                aF[mr][ks], bF[nc][ks], acc[qr][qc][mr][nc], 0, 0, 0);
      __builtin_amdgcn_s_setprio(0);
    };

    // Prologue: K-tile 0 fully + first 3 halves of K-tile 1.
#pragma unroll
    for (int H = 0; H < 4; ++H) stage(H);
    asm volatile("s_waitcnt vmcnt(4)" ::: "memory");
#pragma unroll
    for (int H = 4; H < 7; ++H) stage(H);

#pragma unroll 2
    for (int kt = 0; kt < NKt - 1; ++kt) {
      char* vA = (kt & 1) ? vA1 : vA0;
      char* vB = (kt & 1) ? vB1 : vB0;
      asm volatile("s_waitcnt vmcnt(6)" ::: "memory");
      __builtin_amdgcn_s_barrier();
      loadA(vA, 0);
      loadB(vB, 0, bF0);
      { int H = 4 * kt + 7;  if (H < 4 * NKt) stage(H); }
      __builtin_amdgcn_s_barrier();
      mfmaQ(0, 0, bF0);
      __builtin_amdgcn_s_barrier();
      loadB(vB, 1, bF1);
      { int H = 4 * kt + 8;  if (H < 4 * NKt) stage(H); }
      __builtin_amdgcn_s_barrier();
      mfmaQ(0, 1, bF1);
      __builtin_amdgcn_s_barrier();
      loadA(vA, 1);
      { int H = 4 * kt + 9;  if (H < 4 * NKt) stage(H); }
      __builtin_amdgcn_s_barrier();
      mfmaQ(1, 0, bF0);
      __builtin_amdgcn_s_barrier();
      { int H = 4 * kt + 10; if (H < 4 * NKt) stage(H); }
      __builtin_amdgcn_s_barrier();
      mfmaQ(1, 1, bF1);
    }
    {
      char* vA = ((NKt - 1) & 1) ? vA1 : vA0;
      char* vB = ((NKt - 1) & 1) ? vB1 : vB0;
      asm volatile("s_waitcnt vmcnt(0)" ::: "memory");
      __builtin_amdgcn_s_barrier();
      loadA(vA, 0);
      loadB(vB, 0, bF0);
      __builtin_amdgcn_s_barrier();
      mfmaQ(0, 0, bF0);
      __builtin_amdgcn_s_barrier();
      loadB(vB, 1, bF1);
      __builtin_amdgcn_s_barrier();
      mfmaQ(0, 1, bF1);
      __builtin_amdgcn_s_barrier();
      loadA(vA, 1);
      __builtin_amdgcn_s_barrier();
      mfmaQ(1, 0, bF0);
      __builtin_amdgcn_s_barrier();
      mfmaQ(1, 1, bF1);
    }

    // Epilogue.  D frag: row = base + (l>>4)*4 + reg, col = base + (l&15).
    const int lr4 = (l >> 4) * 4;
    const int lc  = l & 15;
#pragma unroll
    for (int qr = 0; qr < 2; ++qr)
#pragma unroll
      for (int mr = 0; mr < 4; ++mr)
#pragma unroll
        for (int rg = 0; rg < 4; ++rg) {
          int row = qr * 128 + r0 + mr * 16 + lr4 + rg;
          if (row < nr) {
            if constexpr (OUTBF) {
              unsigned short* dst = out_bf + (size_t)(rs + row) * N + n0;
#pragma unroll
              for (int qc = 0; qc < 2; ++qc)
#pragma unroll
                for (int nc = 0; nc < 2; ++nc) {
                  float v = acc[qr][qc][mr][nc][rg];
                  if constexpr (GELU) v = gelu_fast(v);
                  dst[qc * 128 + c0 + nc * 16 + lc] = f2bf(v);
                }
            } else {
              int orig = perm[rs + row];
              float* dst = out_f + (size_t)orig * N + n0;
#pragma unroll
              for (int qc = 0; qc < 2; ++qc)
#pragma unroll
                for (int nc = 0; nc < 2; ++nc) {
                  float v = acc[qr][qc][mr][nc][rg];
                  if constexpr (BIAS)
                    v += bias[(size_t)e * N + n0 + qc * 128 + c0 + nc * 16 + lc];
                  dst[qc * 128 + c0 + nc * 16 + lc] = v;
                }
            }
          }
        }
  }

  if constexpr (CONVTAIL) {
    const size_t stride = (size_t)gridDim.x * 512;
    for (size_t u = (size_t)bid * 512 + t; u < (size_t)kCN2; u += stride) {
      const float4* s = (const float4*)(csrc + u * 8);
      float4 f0 = s[0], f1 = s[1];
      short8 v;
      v[0] = (short)f2bf(f0.x); v[1] = (short)f2bf(f0.y);
      v[2] = (short)f2bf(f0.z); v[3] = (short)f2bf(f0.w);
      v[4] = (short)f2bf(f1.x); v[5] = (short)f2bf(f1.y);
      v[6] = (short)f2bf(f1.z); v[7] = (short)f2bf(f1.w);
      *(short8*)(cdst + u * 8) = v;
    }
  }
}

// ---------------------------------------------------------------------------
extern "C" void kernel_launch(void* const* d_in, const int* in_sizes, int n_in,
                              void* d_out, int out_size, void* d_ws, size_t ws_size,
                              hipStream_t stream) {
  const float* x  = (const float*)d_in[0];
  const int*  eid = (const int*)d_in[1];
  const float* W1 = (const float*)d_in[2];
  const float* W2 = (const float*)d_in[3];
  const float* b2 = (const float*)d_in[4];
  float* y = (float*)d_out;

  char* ws = (char*)d_ws;
  int* perm  = (int*)ws;                                   // 32KB
  int* tiles = (int*)(ws + 32768);
  unsigned short* xg = (unsigned short*)(ws + 36864);
  size_t xg_bytes = (size_t)(kB + 256) * kD * 2;
  unsigned short* h  = (unsigned short*)(ws + 36864 + xg_bytes);
  size_t h_bytes = (size_t)(kB + 256) * kH1 * 2;
  size_t w1b_off = 36864 + xg_bytes + h_bytes;
  unsigned short* W1b = (unsigned short*)(ws + w1b_off);
  size_t w2b_off = w1b_off + 67108864;
  const bool twobuf = ws_size >= w2b_off + 67108864;
  unsigned short* W2b = twobuf ? (unsigned short*)(ws + w2b_off) : W1b;

  auto g1f = gemm8p_kernel<kD, kH1, true, false, true, true>;
  auto g1s = gemm8p_kernel<kD, kH1, true, false, true, false>;
  auto g2  = gemm8p_kernel<kH1, kO, false, true, false, false>;
  hipFuncSetAttribute((const void*)g1f, hipFuncAttributeMaxDynamicSharedMemorySize, 131072);
  hipFuncSetAttribute((const void*)g1s, hipFuncAttributeMaxDynamicSharedMemorySize, 131072);
  hipFuncSetAttribute((const void*)g2,  hipFuncAttributeMaxDynamicSharedMemorySize, 131072);

  setup_kernel<<<1, 256, 0, stream>>>(eid, perm, tiles);
  gatherconv_kernel<<<2048, 256, 0, stream>>>(x, perm, xg, W1, W1b);

  if (twobuf) {
    g1f<<<MAXT * (kH1 / 256), 512, 131072, stream>>>(
        xg, W1b, nullptr, tiles, perm, h, nullptr, W2, W2b);
  } else {
    g1s<<<MAXT * (kH1 / 256), 512, 131072, stream>>>(
        xg, W1b, nullptr, tiles, perm, h, nullptr, nullptr, nullptr);
    convert_kernel<<<2048, 256, 0, stream>>>(W2, W2b, kCN2);
  }

  g2<<<MAXT * (kO / 256), 512, 131072, stream>>>(
      h, W2b, b2, tiles, perm, nullptr, y, nullptr, nullptr);
}